// Round 2
// baseline (386.970 us; speedup 1.0000x reference)
//
#include <hip/hip_runtime.h>
#include <hip/hip_bf16.h>

typedef unsigned short ushort_t;
typedef __bf16 bf16x8 __attribute__((ext_vector_type(8)));
typedef __bf16 bf16x4 __attribute__((ext_vector_type(4)));
typedef float  f32x4  __attribute__((ext_vector_type(4)));

#define G_      16
#define CIN_    128
#define H_      256
#define PD_     256
#define BM_     128
#define THREADS_ 512

// ws layout (in ushort elements)
#define W1_OFF  0
#define W2_OFF  (16*256*128)            // 524288
#define W3_OFF  (W2_OFF + 16*256*256)   // 1572864
#define WO_OFF  (W3_OFF + 16*256*256)   // 2621440
#define W_TOTAL (WO_OFF + 16*256*256)   // 3670016 elems = 7.34 MB

// ---------------- weight fp32 -> bf16 conversion ----------------
__global__ void convert_weights_kernel(const float* __restrict__ W1,
                                       const float* __restrict__ W2,
                                       const float* __restrict__ W3,
                                       const float* __restrict__ Wo,
                                       ushort_t* __restrict__ dst) {
  size_t i = ((size_t)blockIdx.x * blockDim.x + threadIdx.x) * 4;
  const float* src; size_t off;
  if (i < (size_t)W2_OFF)      { src = W1; off = i; }
  else if (i < (size_t)W3_OFF) { src = W2; off = i - W2_OFF; }
  else if (i < (size_t)WO_OFF) { src = W3; off = i - W3_OFF; }
  else                         { src = Wo; off = i - WO_OFF; }
  const float4 v = *reinterpret_cast<const float4*>(src + off);
  bf16x4 o;
  o[0] = (__bf16)v.x; o[1] = (__bf16)v.y; o[2] = (__bf16)v.z; o[3] = (__bf16)v.w;
  *reinterpret_cast<bf16x4*>(dst + i) = o;
}

// ---------------- fused grouped-MLP decoder ----------------
__device__ __forceinline__ void zero_acc(f32x4 acc[4][4]) {
#pragma unroll
  for (int i = 0; i < 4; ++i)
#pragma unroll
    for (int j = 0; j < 4; ++j)
      acc[i][j] = (f32x4){0.0f, 0.0f, 0.0f, 0.0f};
}

// One [128 x 256] (= full block tile) GEMM step: C += A(hbuf, bf16, swizzled) * W^T.
// W layout: [n][k] row-major bf16, row length K = KSTEPS*32.
// A/B fragments use identical (lane,elem)->k mapping, so the exact HW k-order cancels.
template<int KSTEPS, int ROWB>
__device__ __forceinline__ void gemm_tile(const char* hb, const ushort_t* Wg,
                                          int rowbase, int colbase,
                                          int l15, int khi, f32x4 acc[4][4]) {
  int rb[4], sw[4];
#pragma unroll
  for (int mi = 0; mi < 4; ++mi) {
    const int r = rowbase + mi * 16 + l15;
    rb[mi] = r * ROWB;
    sw[mi] = (r & 7) << 4;
  }
  const ushort_t* wp[4];
#pragma unroll
  for (int ni = 0; ni < 4; ++ni)
    wp[ni] = Wg + (size_t)(colbase + ni * 16 + l15) * (KSTEPS * 32);

#pragma unroll
  for (int ks = 0; ks < KSTEPS; ++ks) {
    const int kb = ks * 64 + khi * 16;   // byte offset within A row
    const int kk = ks * 32 + khi * 8;    // element offset within W row
    bf16x8 a[4], b[4];
#pragma unroll
    for (int mi = 0; mi < 4; ++mi)
      a[mi] = *reinterpret_cast<const bf16x8*>(hb + rb[mi] + (kb ^ sw[mi]));
#pragma unroll
    for (int ni = 0; ni < 4; ++ni)
      b[ni] = *reinterpret_cast<const bf16x8*>(wp[ni] + kk);
#pragma unroll
    for (int mi = 0; mi < 4; ++mi)
#pragma unroll
      for (int ni = 0; ni < 4; ++ni)
        acc[mi][ni] = __builtin_amdgcn_mfma_f32_16x16x32_bf16(a[mi], b[ni], acc[mi][ni], 0, 0, 0);
  }
}

__global__ __launch_bounds__(THREADS_, 4) void fused_decoder(
    const float* __restrict__ z1, const float* __restrict__ z2,
    const ushort_t* __restrict__ Wall,
    const float* __restrict__ b1, const float* __restrict__ b2,
    const float* __restrict__ b3, const float* __restrict__ bo,
    float* __restrict__ out)
{
  __shared__ __align__(16) char hbuf[65536];   // [128 rows][<=512B], XOR-swizzled bf16

  const int tid  = threadIdx.x;
  const int lane = tid & 63;
  const int wid  = tid >> 6;      // 0..7
  const int wm   = wid >> 2;      // 0..1
  const int wn   = wid & 3;       // 0..3
  const int l15  = lane & 15;
  const int khi  = lane >> 4;     // 0..3
  const int rowbase = wm * 64;
  const int colbase = wn * 64;

  // XCD-aware mapping: 2 groups per XCD -> per-XCD L2 weight footprint ~0.9 MB
  const int bid  = blockIdx.x;        // 0..1023
  const int xcd  = bid & 7;
  const int idx  = bid >> 3;          // 0..127
  const int g    = xcd * 2 + (idx >> 6);
  const int tile = idx & 63;
  const int row0 = tile * BM_;

  // ---- stage z tile (fp32 global -> bf16 LDS, row stride 256B) ----
  {
    const int r = tid >> 2;           // 0..127 row within tile
    const int q = tid & 3;            // 0..3: z1 lo / z1 hi / z2 lo / z2 hi
    const float* src = (q < 2) ? z1 : z2;
    const float* p = src + (size_t)(row0 + r) * (G_ * 64) + g * 64 + (q & 1) * 32;
    char* drow = hbuf + r * 256;
    const int swr = (r & 7) << 4;
#pragma unroll
    for (int it = 0; it < 4; ++it) {
      const float4 va = *reinterpret_cast<const float4*>(p + it * 8);
      const float4 vb = *reinterpret_cast<const float4*>(p + it * 8 + 4);
      bf16x8 o;
      o[0] = (__bf16)va.x; o[1] = (__bf16)va.y; o[2] = (__bf16)va.z; o[3] = (__bf16)va.w;
      o[4] = (__bf16)vb.x; o[5] = (__bf16)vb.y; o[6] = (__bf16)vb.z; o[7] = (__bf16)vb.w;
      const int kb = q * 64 + it * 16;
      *reinterpret_cast<bf16x8*>(drow + (kb ^ swr)) = o;
    }
  }
  __syncthreads();

  f32x4 acc[4][4];

  // ---------------- layer 1: h1 = relu(W1 z + b1), K=128 ----------------
  zero_acc(acc);
  gemm_tile<4, 256>(hbuf, Wall + W1_OFF + (size_t)g * H_ * CIN_, rowbase, colbase, l15, khi, acc);
  __syncthreads();   // all reads of z done before overwriting hbuf
  {
    const float* bg = b1 + g * H_;
#pragma unroll
    for (int ni = 0; ni < 4; ++ni) {
      const int col = colbase + ni * 16 + l15;
      const float bias = bg[col];
#pragma unroll
      for (int mi = 0; mi < 4; ++mi) {
#pragma unroll
        for (int rr = 0; rr < 4; ++rr) {
          const int row = rowbase + mi * 16 + khi * 4 + rr;
          const float v = fmaxf(acc[mi][ni][rr] + bias, 0.0f);
          *reinterpret_cast<__bf16*>(hbuf + row * 512 + ((col * 2) ^ ((row & 7) << 4))) = (__bf16)v;
        }
      }
    }
  }
  __syncthreads();

  // ---------------- layers 2,3: h = relu(W h + b) + h, K=256 ----------------
  const ushort_t* WL[2] = { Wall + W2_OFF + (size_t)g * H_ * H_,
                            Wall + W3_OFF + (size_t)g * H_ * H_ };
  const float* BL[2] = { b2 + g * H_, b3 + g * H_ };
  for (int L = 0; L < 2; ++L) {
    zero_acc(acc);
    gemm_tile<8, 512>(hbuf, WL[L], rowbase, colbase, l15, khi, acc);
    __syncthreads();  // all reads of h done
    const float* bg = BL[L];
#pragma unroll
    for (int ni = 0; ni < 4; ++ni) {
      const int col = colbase + ni * 16 + l15;
      const float bias = bg[col];
#pragma unroll
      for (int mi = 0; mi < 4; ++mi) {
#pragma unroll
        for (int rr = 0; rr < 4; ++rr) {
          const int row = rowbase + mi * 16 + khi * 4 + rr;
          char* hp = hbuf + row * 512 + ((col * 2) ^ ((row & 7) << 4));
          const float old = (float)(*reinterpret_cast<__bf16*>(hp));  // residual (owner-only RMW)
          const float v = fmaxf(acc[mi][ni][rr] + bias, 0.0f) + old;
          *reinterpret_cast<__bf16*>(hp) = (__bf16)v;
        }
      }
    }
    __syncthreads();
  }

  // ---------------- output layer: out = Wo h + bo, K=256, fp32 store ----------------
  zero_acc(acc);
  gemm_tile<8, 512>(hbuf, Wall + WO_OFF + (size_t)g * PD_ * H_, rowbase, colbase, l15, khi, acc);
  {
    const float* bg = bo + g * PD_;
#pragma unroll
    for (int ni = 0; ni < 4; ++ni) {
      const int col = colbase + ni * 16 + l15;
      const float bias = bg[col];
#pragma unroll
      for (int mi = 0; mi < 4; ++mi) {
#pragma unroll
        for (int rr = 0; rr < 4; ++rr) {
          const int row = rowbase + mi * 16 + khi * 4 + rr;
          out[(size_t)(row0 + row) * (G_ * PD_) + g * PD_ + col] = acc[mi][ni][rr] + bias;
        }
      }
    }
  }
}

extern "C" void kernel_launch(void* const* d_in, const int* in_sizes, int n_in,
                              void* d_out, int out_size, void* d_ws, size_t ws_size,
                              hipStream_t stream) {
  const float* z1 = (const float*)d_in[0];
  const float* z2 = (const float*)d_in[1];
  const float* W1 = (const float*)d_in[2];
  const float* b1 = (const float*)d_in[3];
  const float* W2 = (const float*)d_in[4];
  const float* b2 = (const float*)d_in[5];
  const float* W3 = (const float*)d_in[6];
  const float* b3 = (const float*)d_in[7];
  const float* Wo = (const float*)d_in[8];
  const float* bo = (const float*)d_in[9];
  float* out = (float*)d_out;
  ushort_t* Wall = (ushort_t*)d_ws;

  // fp32 -> bf16 weight conversion (7.34 MB into d_ws), every call (ws is re-poisoned)
  convert_weights_kernel<<<W_TOTAL / 4 / 256, 256, 0, stream>>>(W1, W2, W3, Wo, Wall);

  // fused decoder: 16 groups x 64 row-tiles of 128
  fused_decoder<<<1024, THREADS_, 0, stream>>>(z1, z2, Wall, b1, b2, b3, bo, out);
}

// Round 11
// 353.340 us; speedup vs baseline: 1.0952x; 1.0952x over previous
//
#include <hip/hip_runtime.h>
#include <hip/hip_bf16.h>

typedef unsigned short ushort_t;
typedef __bf16 bf16x8 __attribute__((ext_vector_type(8)));
typedef __bf16 bf16x4 __attribute__((ext_vector_type(4)));
typedef float  f32x4  __attribute__((ext_vector_type(4)));

#define G_      16
#define CIN_    128
#define H_      256
#define PD_     256
#define BM_     128
#define THREADS_ 512

// ws layout (in ushort elements)
#define W1_OFF  0
#define W2_OFF  (16*256*128)            // 524288
#define W3_OFF  (W2_OFF + 16*256*256)   // 1572864
#define WO_OFF  (W3_OFF + 16*256*256)   // 2621440
#define W_TOTAL (WO_OFF + 16*256*256)   // 3670016 elems = 7.34 MB

// ---------------- weight fp32 -> bf16 conversion ----------------
__global__ void convert_weights_kernel(const float* __restrict__ W1,
                                       const float* __restrict__ W2,
                                       const float* __restrict__ W3,
                                       const float* __restrict__ Wo,
                                       ushort_t* __restrict__ dst) {
  size_t i = ((size_t)blockIdx.x * blockDim.x + threadIdx.x) * 4;
  const float* src; size_t off;
  if (i < (size_t)W2_OFF)      { src = W1; off = i; }
  else if (i < (size_t)W3_OFF) { src = W2; off = i - W2_OFF; }
  else if (i < (size_t)WO_OFF) { src = W3; off = i - W3_OFF; }
  else                         { src = Wo; off = i - WO_OFF; }
  const f32x4 v = *reinterpret_cast<const f32x4*>(src + off);
  bf16x4 o;
  o[0] = (__bf16)v[0]; o[1] = (__bf16)v[1]; o[2] = (__bf16)v[2]; o[3] = (__bf16)v[3];
  *reinterpret_cast<bf16x4*>(dst + i) = o;
}

// ---------------- fused grouped-MLP decoder ----------------
__device__ __forceinline__ void zero_acc(f32x4 acc[4][4]) {
#pragma unroll
  for (int i = 0; i < 4; ++i)
#pragma unroll
    for (int j = 0; j < 4; ++j)
      acc[i][j] = (f32x4){0.0f, 0.0f, 0.0f, 0.0f};
}

// One [128 x 256] (= full block tile) GEMM step: C += A(hbuf, bf16, swizzled) * W^T.
// W layout: [n][k] row-major bf16, row length K = KSTEPS*32.
// A/B fragments use identical (lane,elem)->k mapping, so the exact HW k-order cancels.
template<int KSTEPS, int ROWB>
__device__ __forceinline__ void gemm_tile(const char* hb, const ushort_t* Wg,
                                          int rowbase, int colbase,
                                          int l15, int khi, f32x4 acc[4][4]) {
  int rb[4], sw[4];
#pragma unroll
  for (int mi = 0; mi < 4; ++mi) {
    const int r = rowbase + mi * 16 + l15;
    rb[mi] = r * ROWB;
    sw[mi] = (r & 7) << 4;
  }
  const ushort_t* wp[4];
#pragma unroll
  for (int ni = 0; ni < 4; ++ni)
    wp[ni] = Wg + (size_t)(colbase + ni * 16 + l15) * (KSTEPS * 32);

#pragma unroll
  for (int ks = 0; ks < KSTEPS; ++ks) {
    const int kb = ks * 64 + khi * 16;   // byte offset within A row
    const int kk = ks * 32 + khi * 8;    // element offset within W row
    bf16x8 a[4], b[4];
#pragma unroll
    for (int mi = 0; mi < 4; ++mi)
      a[mi] = *reinterpret_cast<const bf16x8*>(hb + rb[mi] + (kb ^ sw[mi]));
#pragma unroll
    for (int ni = 0; ni < 4; ++ni)
      b[ni] = *reinterpret_cast<const bf16x8*>(wp[ni] + kk);
#pragma unroll
    for (int mi = 0; mi < 4; ++mi)
#pragma unroll
      for (int ni = 0; ni < 4; ++ni)
        acc[mi][ni] = __builtin_amdgcn_mfma_f32_16x16x32_bf16(a[mi], b[ni], acc[mi][ni], 0, 0, 0);
  }
}

__global__ __launch_bounds__(THREADS_, 2) void fused_decoder(
    const float* __restrict__ z1, const float* __restrict__ z2,
    const ushort_t* __restrict__ Wall,
    const float* __restrict__ b1, const float* __restrict__ b2,
    const float* __restrict__ b3, const float* __restrict__ bo,
    float* __restrict__ out)
{
  __shared__ __align__(16) char hbuf[65536];   // [128 rows][<=512B], XOR-swizzled bf16

  const int tid  = threadIdx.x;
  const int lane = tid & 63;
  const int wid  = tid >> 6;      // 0..7
  const int wm   = wid >> 2;      // 0..1
  const int wn   = wid & 3;       // 0..3
  const int l15  = lane & 15;
  const int khi  = lane >> 4;     // 0..3
  const int rowbase = wm * 64;
  const int colbase = wn * 64;

  // XCD-aware mapping: 2 groups per XCD -> per-XCD L2 weight footprint ~0.9 MB
  const int bid  = blockIdx.x;        // 0..1023
  const int xcd  = bid & 7;
  const int idx  = bid >> 3;          // 0..127
  const int g    = xcd * 2 + (idx >> 6);
  const int tile = idx & 63;
  const int row0 = tile * BM_;

  // ---- stage z tile (fp32 global -> bf16 LDS, row stride 256B) ----
  {
    const int r = tid >> 2;           // 0..127 row within tile
    const int q = tid & 3;            // 0..3: z1 lo / z1 hi / z2 lo / z2 hi
    const float* src = (q < 2) ? z1 : z2;
    const float* p = src + (size_t)(row0 + r) * (G_ * 64) + g * 64 + (q & 1) * 32;
    char* drow = hbuf + r * 256;
    const int swr = (r & 7) << 4;
#pragma unroll
    for (int it = 0; it < 4; ++it) {
      const f32x4 va = __builtin_nontemporal_load(reinterpret_cast<const f32x4*>(p + it * 8));
      const f32x4 vb = __builtin_nontemporal_load(reinterpret_cast<const f32x4*>(p + it * 8 + 4));
      bf16x8 o;
      o[0] = (__bf16)va[0]; o[1] = (__bf16)va[1]; o[2] = (__bf16)va[2]; o[3] = (__bf16)va[3];
      o[4] = (__bf16)vb[0]; o[5] = (__bf16)vb[1]; o[6] = (__bf16)vb[2]; o[7] = (__bf16)vb[3];
      const int kb = q * 64 + it * 16;
      *reinterpret_cast<bf16x8*>(drow + (kb ^ swr)) = o;
    }
  }
  __syncthreads();

  f32x4 acc[4][4];

  // ---------------- layer 1: h1 = relu(W1 z + b1), K=128 ----------------
  zero_acc(acc);
  gemm_tile<4, 256>(hbuf, Wall + W1_OFF + (size_t)g * H_ * CIN_, rowbase, colbase, l15, khi, acc);
  __syncthreads();   // all reads of z done before overwriting hbuf
  {
    const float* bg = b1 + g * H_;
#pragma unroll
    for (int ni = 0; ni < 4; ++ni) {
      const int col = colbase + ni * 16 + l15;
      const float bias = bg[col];
#pragma unroll
      for (int mi = 0; mi < 4; ++mi) {
#pragma unroll
        for (int rr = 0; rr < 4; ++rr) {
          const int row = rowbase + mi * 16 + khi * 4 + rr;
          const float v = fmaxf(acc[mi][ni][rr] + bias, 0.0f);
          *reinterpret_cast<__bf16*>(hbuf + row * 512 + ((col * 2) ^ ((row & 7) << 4))) = (__bf16)v;
        }
      }
    }
  }
  __syncthreads();

  // ---------------- layers 2,3: h = relu(W h + b) + h, K=256 ----------------
  const ushort_t* WL[2] = { Wall + W2_OFF + (size_t)g * H_ * H_,
                            Wall + W3_OFF + (size_t)g * H_ * H_ };
  const float* BL[2] = { b2 + g * H_, b3 + g * H_ };
  for (int L = 0; L < 2; ++L) {
    zero_acc(acc);
    gemm_tile<8, 512>(hbuf, WL[L], rowbase, colbase, l15, khi, acc);
    __syncthreads();  // all reads of h done
    const float* bg = BL[L];
#pragma unroll
    for (int ni = 0; ni < 4; ++ni) {
      const int col = colbase + ni * 16 + l15;
      const float bias = bg[col];
#pragma unroll
      for (int mi = 0; mi < 4; ++mi) {
#pragma unroll
        for (int rr = 0; rr < 4; ++rr) {
          const int row = rowbase + mi * 16 + khi * 4 + rr;
          char* hp = hbuf + row * 512 + ((col * 2) ^ ((row & 7) << 4));
          const float old = (float)(*reinterpret_cast<__bf16*>(hp));  // residual (owner-only RMW)
          const float v = fmaxf(acc[mi][ni][rr] + bias, 0.0f) + old;
          *reinterpret_cast<__bf16*>(hp) = (__bf16)v;
        }
      }
    }
    __syncthreads();
  }

  // ---------------- output layer: out = Wo h + bo, K=256, fp32 nt-store ----------------
  zero_acc(acc);
  gemm_tile<8, 512>(hbuf, Wall + WO_OFF + (size_t)g * PD_ * H_, rowbase, colbase, l15, khi, acc);
  {
    const float* bg = bo + g * PD_;
#pragma unroll
    for (int ni = 0; ni < 4; ++ni) {
      const int col = colbase + ni * 16 + l15;
      const float bias = bg[col];
#pragma unroll
      for (int mi = 0; mi < 4; ++mi) {
#pragma unroll
        for (int rr = 0; rr < 4; ++rr) {
          const int row = rowbase + mi * 16 + khi * 4 + rr;
          __builtin_nontemporal_store(acc[mi][ni][rr] + bias,
              out + (size_t)(row0 + row) * (G_ * PD_) + g * PD_ + col);
        }
      }
    }
  }
}

extern "C" void kernel_launch(void* const* d_in, const int* in_sizes, int n_in,
                              void* d_out, int out_size, void* d_ws, size_t ws_size,
                              hipStream_t stream) {
  const float* z1 = (const float*)d_in[0];
  const float* z2 = (const float*)d_in[1];
  const float* W1 = (const float*)d_in[2];
  const float* b1 = (const float*)d_in[3];
  const float* W2 = (const float*)d_in[4];
  const float* b2 = (const float*)d_in[5];
  const float* W3 = (const float*)d_in[6];
  const float* b3 = (const float*)d_in[7];
  const float* Wo = (const float*)d_in[8];
  const float* bo = (const float*)d_in[9];
  float* out = (float*)d_out;
  ushort_t* Wall = (ushort_t*)d_ws;

  // fp32 -> bf16 weight conversion (7.34 MB into d_ws), every call (ws is re-poisoned)
  convert_weights_kernel<<<W_TOTAL / 4 / 256, 256, 0, stream>>>(W1, W2, W3, Wo, Wall);

  // fused decoder: 16 groups x 64 row-tiles of 128
  fused_decoder<<<1024, THREADS_, 0, stream>>>(z1, z2, Wall, b1, b2, b3, bo, out);
}